// Round 1
// baseline (12194.142 us; speedup 1.0000x reference)
//
#include <hip/hip_runtime.h>

#define TSEQ 512
#define NJ   64

typedef unsigned short us8v __attribute__((ext_vector_type(8)));
typedef __bf16 bf16x8 __attribute__((ext_vector_type(8)));
typedef float f32x4 __attribute__((ext_vector_type(4)));

// ---- workspace layout (bytes) ----
#define OFF_FLAGS   0u
#define OFF_BIAS    8192u          // 2*2048 f32 (b_ih+b_hh per layer)
#define OFF_X16     32768u         // x as bf16 [64][512][64]
#define OFF_W0      4227072u       // Wcat0 bf16 [2048][576]  (W_ih0 | W_hh0)
#define OFF_W1      6586368u       // Wcat1 bf16 [2048][1024] (W_ih1 | W_hh1)
#define OFF_Y0      10780672u      // y0 bf16 [512][64][512] (h0 sequence = layer1 input)
#define OFF_RING    44335104u      // h1 ring bf16 [2][64][512]

static __device__ __forceinline__ unsigned short f2bf(float f) {
    unsigned u = __builtin_bit_cast(unsigned, f);
    u += 0x7fffu + ((u >> 16) & 1u);            // RNE
    return (unsigned short)(u >> 16);
}
static __device__ __forceinline__ float sigmf(float x) { return 1.0f / (1.0f + __expf(-x)); }
static __device__ __forceinline__ float tanh_fast(float x) {
    float a = fabsf(x);
    float e = __expf(-2.0f * a);
    float t = (1.0f - e) / (1.0f + e);
    return copysignf(t, x);
}
static __device__ __forceinline__ f32x4 mfma16(us8v a, us8v b, f32x4 c) {
    return __builtin_amdgcn_mfma_f32_16x16x32_bf16(
        __builtin_bit_cast(bf16x8, a), __builtin_bit_cast(bf16x8, b), c, 0, 0, 0);
}

// ---------------- setup: fp32 -> bf16 conversions + concatenated weights ----------------
__global__ void setup_kernel(const float* __restrict__ x,
                             const float* __restrict__ wih0, const float* __restrict__ whh0,
                             const float* __restrict__ bih0, const float* __restrict__ bhh0,
                             const float* __restrict__ wih1, const float* __restrict__ whh1,
                             const float* __restrict__ bih1, const float* __restrict__ bhh1,
                             char* __restrict__ ws)
{
    unsigned idx = blockIdx.x * blockDim.x + threadIdx.x;
    unsigned stride = gridDim.x * blockDim.x;
    unsigned short* x16 = (unsigned short*)(ws + OFF_X16);
    unsigned short* w0  = (unsigned short*)(ws + OFF_W0);
    unsigned short* w1  = (unsigned short*)(ws + OFF_W1);
    float* bias = (float*)(ws + OFF_BIAS);
    const unsigned NX  = 64u*512u*64u;      // 2097152
    const unsigned NW0 = 2048u*576u;        // 1179648
    const unsigned NW1 = 2048u*1024u;       // 2097152
    const unsigned NT  = NX + NW0 + NW1 + 4096u;
    for (unsigned i = idx; i < NT; i += stride) {
        if (i < NX) {
            x16[i] = f2bf(x[i]);
        } else if (i < NX + NW0) {
            unsigned k = i - NX; unsigned r = k / 576u, c = k % 576u;
            float v = (c < 64u) ? wih0[r*64u + c] : whh0[r*512u + (c - 64u)];
            w0[k] = f2bf(v);
        } else if (i < NX + NW0 + NW1) {
            unsigned k = i - NX - NW0; unsigned r = k >> 10, c = k & 1023u;
            float v = (c < 512u) ? wih1[(r<<9) + c] : whh1[(r<<9) + (c - 512u)];
            w1[k] = f2bf(v);
        } else {
            unsigned k = i - NX - NW0 - NW1;   // 0..4095
            float v = (k < 2048u) ? (bih0[k] + bhh0[k]) : (bih1[k-2048u] + bhh1[k-2048u]);
            bias[k] = v;
        }
    }
}

// ---------------- persistent recurrence kernel ----------------
// 64 blocks; block j owns h-indices [j*8, j*8+8) -> 32 gate rows (i,f,g,o).
// W slice register-resident as MFMA A-frags; per-step h broadcast via global
// memory + agent-scope flag counters.
__launch_bounds__(256, 1)
__global__ void lstm_persist(char* __restrict__ ws)
{
    const int tid  = threadIdx.x;
    const int j    = blockIdx.x;
    const int wv   = tid >> 6;      // wave id = batch n-tile
    const int lane = tid & 63;
    const int l15  = lane & 15;
    const int lhi  = lane >> 4;

    unsigned* flags   = (unsigned*)(ws + OFF_FLAGS);
    const float* bias = (const float*)(ws + OFF_BIAS);
    const char* x16 = ws + OFF_X16;
    char* y0   = ws + OFF_Y0;
    char* ring = ws + OFF_RING;

    __shared__ __align__(16) char zbuf[131072];   // z staged [64 batch][K] bf16, XOR-swizzled
    __shared__ float gsum[32][66];                // gate pre-activations (padded stride)
    __shared__ float bias_l[32];

    if (tid < 32) bias_l[tid] = bias[((tid >> 3) << 9) + j*8 + (tid & 7)];

    // per-thread cell state: thread (b = tid&63, p0 = (tid>>6)*2) owns c[b][p0], c[b][p0+1]
    float c0 = 0.0f, c1 = 0.0f;

    // A-fragments (register resident). index kt*2+m ; layer0 uses [0..35], layer1 [0..63]
    us8v Areg[64];
    {
        const char* w0p = ws + OFF_W0;
        #pragma unroll
        for (int kt = 0; kt < 18; ++kt) {
            #pragma unroll
            for (int m = 0; m < 2; ++m) {
                int lr = m*16 + l15;
                int gr = ((lr >> 3) << 9) + j*8 + (lr & 7);    // gate*512 + hidx
                Areg[kt*2+m] = *(const us8v*)(w0p + (size_t)(gr*576 + kt*32 + lhi*8)*2);
            }
        }
    }
    __syncthreads();

    const int zrow = wv*16 + l15;            // B-frag row (batch) this lane reads
    const int swzr = (zrow & 7) << 4;

    // ================= layer 0 : K = 576 = [x_t(64) | h0(512)] =================
    for (int t = 0; t < TSEQ; ++t) {
        if (t > 0 && tid == 0) {
            while (__hip_atomic_load(&flags[t-1], __ATOMIC_ACQUIRE, __HIP_MEMORY_SCOPE_AGENT) < NJ) {}
        }
        __syncthreads();
        // ---- stage z (swizzled writes) ----
        {   // x part: 64 rows x 128B
            #pragma unroll
            for (int i = 0; i < 2; ++i) {
                int c = tid + i*256;
                int b = c >> 3, o16 = c & 7;
                us8v v = *(const us8v*)(x16 + (size_t)((b*512 + t)*64)*2 + o16*16);
                *(us8v*)(zbuf + b*1152 + ((o16*16) ^ ((b & 7) << 4))) = v;
            }
        }
        if (t > 0) {   // h part: 64 rows x 1024B from y0[t-1]
            const char* hsrc = y0 + (size_t)(t-1)*64*1024;
            #pragma unroll 8
            for (int i = 0; i < 16; ++i) {
                int c = tid + i*256;
                int b = c >> 6, o = c & 63;
                us8v v = *(const us8v*)(hsrc + (size_t)b*1024 + o*16);
                *(us8v*)(zbuf + b*1152 + ((128 + o*16) ^ ((b & 7) << 4))) = v;
            }
        }
        __syncthreads();
        // ---- MFMA: D[32 rows][16 batch] per wave ----
        f32x4 acc0 = {0.f,0.f,0.f,0.f}, acc1 = {0.f,0.f,0.f,0.f};
        {
            const int rb = zrow * 1152;
            #pragma unroll
            for (int kt = 0; kt < 2; ++kt) {
                us8v bfrag = *(const us8v*)(zbuf + rb + ((kt*64 + lhi*16) ^ swzr));
                acc0 = mfma16(Areg[kt*2+0], bfrag, acc0);
                acc1 = mfma16(Areg[kt*2+1], bfrag, acc1);
            }
            if (t > 0) {
                #pragma unroll
                for (int kt = 2; kt < 18; ++kt) {
                    us8v bfrag = *(const us8v*)(zbuf + rb + ((kt*64 + lhi*16) ^ swzr));
                    acc0 = mfma16(Areg[kt*2+0], bfrag, acc0);
                    acc1 = mfma16(Areg[kt*2+1], bfrag, acc1);
                }
            }
        }
        #pragma unroll
        for (int q = 0; q < 4; ++q) {
            gsum[lhi*4+q][wv*16+l15]      = acc0[q];   // rows 0..15  (i|f)
            gsum[16+lhi*4+q][wv*16+l15]   = acc1[q];   // rows 16..31 (g|o)
        }
        __syncthreads();
        // ---- activation: thread -> (b, p0..p0+1) ----
        {
            int b = tid & 63, p0 = (tid >> 6) * 2;
            unsigned hw = 0;
            #pragma unroll
            for (int pp = 0; pp < 2; ++pp) {
                int p = p0 + pp;
                float gi = gsum[p][b]      + bias_l[p];
                float gf = gsum[8+p][b]    + bias_l[8+p];
                float gg = gsum[16+p][b]   + bias_l[16+p];
                float go = gsum[24+p][b]   + bias_l[24+p];
                float iv = sigmf(gi), fv = sigmf(gf);
                float gv = tanh_fast(gg), ov = sigmf(go);
                float cc = fv * (pp ? c1 : c0) + iv * gv;
                if (pp) c1 = cc; else c0 = cc;
                float h = ov * tanh_fast(cc);
                hw |= ((unsigned)f2bf(h)) << (16*pp);
            }
            *(unsigned*)(y0 + (size_t)((t*64 + b)*512 + j*8 + p0)*2) = hw;
        }
        __syncthreads();
        if (tid == 0)
            __hip_atomic_fetch_add(&flags[t], 1u, __ATOMIC_RELEASE, __HIP_MEMORY_SCOPE_AGENT);
    }

    // ---- reload A-frags + bias for layer 1 ----
    {
        const char* w1p = ws + OFF_W1;
        #pragma unroll
        for (int kt = 0; kt < 32; ++kt) {
            #pragma unroll
            for (int m = 0; m < 2; ++m) {
                int lr = m*16 + l15;
                int gr = ((lr >> 3) << 9) + j*8 + (lr & 7);
                Areg[kt*2+m] = *(const us8v*)(w1p + (size_t)(gr*1024 + kt*32 + lhi*8)*2);
            }
        }
    }
    if (tid < 32) bias_l[tid] = bias[2048 + ((tid >> 3) << 9) + j*8 + (tid & 7)];
    // c0/c1 carry over: layer1 initial c = layer0 final c (reference quirk)

    // ================= layer 1 : K = 1024 = [y0[t](512) | h1(512)] =================
    for (int t = 0; t < TSEQ; ++t) {
        const int widx = (t == 0) ? 511 : (512 + t - 1);
        if (tid == 0) {
            while (__hip_atomic_load(&flags[widx], __ATOMIC_ACQUIRE, __HIP_MEMORY_SCOPE_AGENT) < NJ) {}
        }
        __syncthreads();
        // ---- stage z: 64 rows x 2048B ----
        {
            const char* s0 = y0 + (size_t)t*64*1024;
            const char* s1 = (t == 0) ? (y0 + (size_t)511*64*1024)             // h1_init = h0_final
                                      : (ring + (size_t)((t-1)&1)*64*1024);
            #pragma unroll 8
            for (int i = 0; i < 32; ++i) {
                int c = tid + i*256;
                int b = c >> 7, o16 = c & 127;
                int off = o16 * 16;
                const char* src = (off < 1024) ? (s0 + (size_t)b*1024 + off)
                                               : (s1 + (size_t)b*1024 + (off - 1024));
                us8v v = *(const us8v*)src;
                *(us8v*)(zbuf + b*2048 + (off ^ ((b & 7) << 4))) = v;
            }
        }
        __syncthreads();
        // ---- MFMA ----
        f32x4 acc0 = {0.f,0.f,0.f,0.f}, acc1 = {0.f,0.f,0.f,0.f};
        {
            const int rb = zrow * 2048;
            #pragma unroll
            for (int kt = 0; kt < 32; ++kt) {
                us8v bfrag = *(const us8v*)(zbuf + rb + ((kt*64 + lhi*16) ^ swzr));
                acc0 = mfma16(Areg[kt*2+0], bfrag, acc0);
                acc1 = mfma16(Areg[kt*2+1], bfrag, acc1);
            }
        }
        #pragma unroll
        for (int q = 0; q < 4; ++q) {
            gsum[lhi*4+q][wv*16+l15]    = acc0[q];
            gsum[16+lhi*4+q][wv*16+l15] = acc1[q];
        }
        __syncthreads();
        {
            int b = tid & 63, p0 = (tid >> 6) * 2;
            unsigned hw = 0;
            #pragma unroll
            for (int pp = 0; pp < 2; ++pp) {
                int p = p0 + pp;
                float gi = gsum[p][b]    + bias_l[p];
                float gf = gsum[8+p][b]  + bias_l[8+p];
                float gg = gsum[16+p][b] + bias_l[16+p];
                float go = gsum[24+p][b] + bias_l[24+p];
                float iv = sigmf(gi), fv = sigmf(gf);
                float gv = tanh_fast(gg), ov = sigmf(go);
                float cc = fv * (pp ? c1 : c0) + iv * gv;
                if (pp) c1 = cc; else c0 = cc;
                float h = ov * tanh_fast(cc);
                hw |= ((unsigned)f2bf(h)) << (16*pp);
            }
            *(unsigned*)(ring + (size_t)(((t&1)*64 + b)*512 + j*8 + p0)*2) = hw;
        }
        __syncthreads();
        if (tid == 0)
            __hip_atomic_fetch_add(&flags[512 + t], 1u, __ATOMIC_RELEASE, __HIP_MEMORY_SCOPE_AGENT);
    }
}

// ---------------- final projection: out = h1_final @ lin_w.T + lin_b ----------------
__global__ void final_linear(const char* __restrict__ ws,
                             const float* __restrict__ linw, const float* __restrict__ linb,
                             float* __restrict__ out)
{
    __shared__ float hrow[512];
    int b = blockIdx.x;        // 64
    int o = threadIdx.x;       // 64
    const char* ring = ws + OFF_RING;
    {
        us8v v = *(const us8v*)(ring + (size_t)(64 + b)*1024 + o*16);  // ring par=1 (t=511)
        #pragma unroll
        for (int p = 0; p < 8; ++p)
            hrow[o*8+p] = __builtin_bit_cast(float, ((unsigned)v[p]) << 16);
    }
    __syncthreads();
    float acc = linb[o];
    const float* wrow = linw + o*512;
    #pragma unroll 8
    for (int k = 0; k < 512; ++k) acc += hrow[k] * wrow[k];
    out[b*64 + o] = acc;
}

extern "C" void kernel_launch(void* const* d_in, const int* in_sizes, int n_in,
                              void* d_out, int out_size, void* d_ws, size_t ws_size,
                              hipStream_t stream)
{
    const float* x    = (const float*)d_in[0];
    const float* wih0 = (const float*)d_in[1];
    const float* whh0 = (const float*)d_in[2];
    const float* bih0 = (const float*)d_in[3];
    const float* bhh0 = (const float*)d_in[4];
    const float* wih1 = (const float*)d_in[5];
    const float* whh1 = (const float*)d_in[6];
    const float* bih1 = (const float*)d_in[7];
    const float* bhh1 = (const float*)d_in[8];
    const float* linw = (const float*)d_in[9];
    const float* linb = (const float*)d_in[10];
    char* ws = (char*)d_ws;

    (void)hipMemsetAsync(ws + OFF_FLAGS, 0, 4096, stream);   // reset step flags each call
    hipLaunchKernelGGL(setup_kernel, dim3(1024), dim3(256), 0, stream,
                       x, wih0, whh0, bih0, bhh0, wih1, whh1, bih1, bhh1, ws);
    hipLaunchKernelGGL(lstm_persist, dim3(NJ), dim3(256), 0, stream, ws);
    hipLaunchKernelGGL(final_linear, dim3(64), dim3(64), 0, stream,
                       ws, linw, linb, (float*)d_out);
}

// Round 2
// 9611.618 us; speedup vs baseline: 1.2687x; 1.2687x over previous
//
#include <hip/hip_runtime.h>

#define TSEQ 512
#define NJ   64

typedef unsigned short us8v __attribute__((ext_vector_type(8)));
typedef __bf16 bf16x8 __attribute__((ext_vector_type(8)));
typedef float f32x4 __attribute__((ext_vector_type(4)));

// ---- workspace layout (bytes) ----
#define OFF_FLAGS 0u            // [1024 steps][64 blocks] u32 = 256 KiB
#define OFF_BIAS  262144u       // 2*2048 f32
#define OFF_X16   278528u       // x bf16 [512 t][64 b][64 d] = 4 MiB
#define OFF_W0    4472832u      // Wcat0 bf16 [2048][576]
#define OFF_W1    6832128u      // Wcat1 bf16 [2048][1024]
#define OFF_Y0    11026432u     // y0 bf16 [512 t][64 j][64 b][8 h] = 32 MiB
#define OFF_RING  44580864u     // h1 ring bf16 [2][64 j][64 b][8 h] = 128 KiB

static __device__ __forceinline__ unsigned short f2bf(float f) {
    unsigned u = __builtin_bit_cast(unsigned, f);
    u += 0x7fffu + ((u >> 16) & 1u);            // RNE
    return (unsigned short)(u >> 16);
}
static __device__ __forceinline__ float sigmf(float x) { return 1.0f / (1.0f + __expf(-x)); }
static __device__ __forceinline__ float tanh_fast(float x) {
    float a = fabsf(x);
    float e = __expf(-2.0f * a);
    float t = (1.0f - e) / (1.0f + e);
    return copysignf(t, x);
}
static __device__ __forceinline__ f32x4 mfma16(us8v a, us8v b, f32x4 c) {
    return __builtin_amdgcn_mfma_f32_16x16x32_bf16(
        __builtin_bit_cast(bf16x8, a), __builtin_bit_cast(bf16x8, b), c, 0, 0, 0);
}

// ---------------- setup: fp32 -> bf16 conversions + concatenated weights ----------------
__global__ void setup_kernel(const float* __restrict__ x,
                             const float* __restrict__ wih0, const float* __restrict__ whh0,
                             const float* __restrict__ bih0, const float* __restrict__ bhh0,
                             const float* __restrict__ wih1, const float* __restrict__ whh1,
                             const float* __restrict__ bih1, const float* __restrict__ bhh1,
                             char* __restrict__ ws)
{
    unsigned idx = blockIdx.x * blockDim.x + threadIdx.x;
    unsigned stride = gridDim.x * blockDim.x;
    unsigned short* x16 = (unsigned short*)(ws + OFF_X16);
    unsigned short* w0  = (unsigned short*)(ws + OFF_W0);
    unsigned short* w1  = (unsigned short*)(ws + OFF_W1);
    float* bias = (float*)(ws + OFF_BIAS);
    const unsigned NX  = 64u*512u*64u;      // 2097152
    const unsigned NW0 = 2048u*576u;        // 1179648
    const unsigned NW1 = 2048u*1024u;       // 2097152
    const unsigned NT  = NX + NW0 + NW1 + 4096u;
    for (unsigned i = idx; i < NT; i += stride) {
        if (i < NX) {
            // transpose to [t][b][d]
            unsigned d = i & 63u, b = (i >> 6) & 63u, t = i >> 12;
            x16[i] = f2bf(x[((b << 9) + t) * 64u + d]);
        } else if (i < NX + NW0) {
            unsigned k = i - NX; unsigned r = k / 576u, c = k % 576u;
            float v = (c < 64u) ? wih0[r*64u + c] : whh0[r*512u + (c - 64u)];
            w0[k] = f2bf(v);
        } else if (i < NX + NW0 + NW1) {
            unsigned k = i - NX - NW0; unsigned r = k >> 10, c = k & 1023u;
            float v = (c < 512u) ? wih1[(r<<9) + c] : whh1[(r<<9) + (c - 512u)];
            w1[k] = f2bf(v);
        } else {
            unsigned k = i - NX - NW0 - NW1;   // 0..4095
            float v = (k < 2048u) ? (bih0[k] + bhh0[k]) : (bih1[k-2048u] + bhh1[k-2048u]);
            bias[k] = v;
        }
    }
}

// ---------------- persistent recurrence kernel ----------------
// 64 blocks; block j owns h-indices [j*8, j*8+8) -> 32 gate rows (i,f,g,o).
// Per-block release-store flags + wave-wide relaxed poll + single acquire fence.
__launch_bounds__(256, 1)
__global__ void lstm_persist(char* __restrict__ ws)
{
    const int tid  = threadIdx.x;
    const int j    = blockIdx.x;
    const int wv   = tid >> 6;      // wave id = batch n-tile
    const int lane = tid & 63;
    const int l15  = lane & 15;
    const int lhi  = lane >> 4;

    unsigned* flags   = (unsigned*)(ws + OFF_FLAGS);
    const float* bias = (const float*)(ws + OFF_BIAS);
    const char* x16 = ws + OFF_X16;
    char* y0   = ws + OFF_Y0;
    char* ring = ws + OFF_RING;

    __shared__ __align__(16) char zbuf[131072];   // z staged [64 batch][K] bf16, XOR-swizzled
    __shared__ float gsum[32][66];                // gate pre-activations (padded stride)
    __shared__ float bias_l[32];

    if (tid < 32) bias_l[tid] = bias[((tid >> 3) << 9) + j*8 + (tid & 7)];

#define WAIT_FLAGS(WIDX) do {                                                          \
        if (wv == 0) {                                                                 \
            const unsigned* fp_ = flags + (size_t)(WIDX)*64 + lane;                    \
            while (!__all((int)__hip_atomic_load(fp_, __ATOMIC_RELAXED,                \
                                                 __HIP_MEMORY_SCOPE_AGENT))) {}        \
            __builtin_amdgcn_fence(__ATOMIC_ACQUIRE, "agent");                         \
        }                                                                              \
        __syncthreads();                                                               \
    } while (0)

    // per-thread cell state: thread (b = tid&63, p0 = (tid>>6)*2) owns c[b][p0], c[b][p0+1]
    float c0 = 0.0f, c1 = 0.0f;

    // A-fragments (register resident). index kt*2+m ; layer0 uses [0..35], layer1 [0..63]
    us8v Areg[64];
    {
        const char* w0p = ws + OFF_W0;
        #pragma unroll
        for (int kt = 0; kt < 18; ++kt) {
            #pragma unroll
            for (int m = 0; m < 2; ++m) {
                int lr = m*16 + l15;
                int gr = ((lr >> 3) << 9) + j*8 + (lr & 7);    // gate*512 + hidx
                Areg[kt*2+m] = *(const us8v*)(w0p + (size_t)(gr*576 + kt*32 + lhi*8)*2);
            }
        }
    }
    __syncthreads();

    const int zrow = wv*16 + l15;            // B-frag row (batch) this lane reads
    const int swzr = (zrow & 7) << 4;

    // ================= layer 0 : K = 576 = [x_t(64) | h0(512)] =================
    for (int t = 0; t < TSEQ; ++t) {
        // ---- x part: 8KB contiguous, no cross-block dependency ----
        #pragma unroll
        for (int i = 0; i < 2; ++i) {
            int c = tid + i*256;
            int b = c >> 3, o16 = c & 7;
            us8v v = *(const us8v*)(x16 + (size_t)t*8192 + (size_t)c*16);
            *(us8v*)(zbuf + b*1152 + ((o16*16) ^ ((b & 7) << 4))) = v;
        }
        if (t > 0) {
            WAIT_FLAGS(t-1);
            // ---- h part: [j][b][16B] chunks, coalesced ----
            const char* hsrc = y0 + (size_t)(t-1)*65536;
            #pragma unroll 8
            for (int i = 0; i < 16; ++i) {
                int c = tid + i*256;
                us8v v = *(const us8v*)(hsrc + (size_t)c*16);
                *(us8v*)(zbuf + (c & 63)*1152 + ((128 + (c >> 6)*16) ^ ((c & 7) << 4))) = v;
            }
        }
        __syncthreads();
        // ---- MFMA: D[32 rows][16 batch] per wave ----
        f32x4 acc0 = {0.f,0.f,0.f,0.f}, acc1 = {0.f,0.f,0.f,0.f};
        {
            const int rb = zrow * 1152;
            #pragma unroll
            for (int kt = 0; kt < 2; ++kt) {
                us8v bfrag = *(const us8v*)(zbuf + rb + ((kt*64 + lhi*16) ^ swzr));
                acc0 = mfma16(Areg[kt*2+0], bfrag, acc0);
                acc1 = mfma16(Areg[kt*2+1], bfrag, acc1);
            }
            if (t > 0) {
                #pragma unroll
                for (int kt = 2; kt < 18; ++kt) {
                    us8v bfrag = *(const us8v*)(zbuf + rb + ((kt*64 + lhi*16) ^ swzr));
                    acc0 = mfma16(Areg[kt*2+0], bfrag, acc0);
                    acc1 = mfma16(Areg[kt*2+1], bfrag, acc1);
                }
            }
        }
        #pragma unroll
        for (int q = 0; q < 4; ++q) {
            gsum[lhi*4+q][wv*16+l15]      = acc0[q];   // rows 0..15  (i|f)
            gsum[16+lhi*4+q][wv*16+l15]   = acc1[q];   // rows 16..31 (g|o)
        }
        __syncthreads();
        // ---- activation ----
        {
            int b = tid & 63, p0 = (tid >> 6) * 2;
            unsigned hw = 0;
            #pragma unroll
            for (int pp = 0; pp < 2; ++pp) {
                int p = p0 + pp;
                float gi = gsum[p][b]      + bias_l[p];
                float gf = gsum[8+p][b]    + bias_l[8+p];
                float gg = gsum[16+p][b]   + bias_l[16+p];
                float go = gsum[24+p][b]   + bias_l[24+p];
                float iv = sigmf(gi), fv = sigmf(gf);
                float gv = tanh_fast(gg), ov = sigmf(go);
                float cc = fv * (pp ? c1 : c0) + iv * gv;
                if (pp) c1 = cc; else c0 = cc;
                float h = ov * tanh_fast(cc);
                hw |= ((unsigned)f2bf(h)) << (16*pp);
            }
            // write-through store: [t][j][b][8]
            __hip_atomic_store((unsigned*)(y0 + (size_t)t*65536 + (size_t)j*1024 + b*16 + (p0 << 1)),
                               hw, __ATOMIC_RELAXED, __HIP_MEMORY_SCOPE_AGENT);
        }
        __syncthreads();
        if (tid == 0)
            __hip_atomic_store(&flags[(size_t)t*64 + j], 1u,
                               __ATOMIC_RELEASE, __HIP_MEMORY_SCOPE_AGENT);
    }

    // ---- reload A-frags + bias for layer 1 ----
    {
        const char* w1p = ws + OFF_W1;
        #pragma unroll
        for (int kt = 0; kt < 32; ++kt) {
            #pragma unroll
            for (int m = 0; m < 2; ++m) {
                int lr = m*16 + l15;
                int gr = ((lr >> 3) << 9) + j*8 + (lr & 7);
                Areg[kt*2+m] = *(const us8v*)(w1p + (size_t)(gr*1024 + kt*32 + lhi*8)*2);
            }
        }
    }
    if (tid < 32) bias_l[tid] = bias[2048 + ((tid >> 3) << 9) + j*8 + (tid & 7)];
    // c0/c1 carry over: layer1 initial c = layer0 final c (reference quirk)

    // ================= layer 1 : K = 1024 = [y0[t](512) | h1(512)] =================
    for (int t = 0; t < TSEQ; ++t) {
        // ---- prefetch y0[t] half (cols 0..1023) — independent of h1[t-1] ----
        {
            const char* s0 = y0 + (size_t)t*65536;
            #pragma unroll 8
            for (int i = 0; i < 16; ++i) {
                int c = tid + i*256;
                us8v v = *(const us8v*)(s0 + (size_t)c*16);
                *(us8v*)(zbuf + (c & 63)*2048 + (((c >> 6)*16) ^ ((c & 7) << 4))) = v;
            }
        }
        __syncthreads();
        // ---- x-half MFMAs while the h flag may still be pending ----
        f32x4 acc0 = {0.f,0.f,0.f,0.f}, acc1 = {0.f,0.f,0.f,0.f};
        const int rb = zrow * 2048;
        #pragma unroll
        for (int kt = 0; kt < 16; ++kt) {
            us8v bfrag = *(const us8v*)(zbuf + rb + ((kt*64 + lhi*16) ^ swzr));
            acc0 = mfma16(Areg[kt*2+0], bfrag, acc0);
            acc1 = mfma16(Areg[kt*2+1], bfrag, acc1);
        }
        const int widx = (t == 0) ? 511 : (511 + t);
        WAIT_FLAGS(widx);
        // ---- stage h half (cols 1024..2047) ----
        {
            const char* s1 = (t == 0) ? (y0 + (size_t)511*65536)
                                      : (ring + (size_t)((t-1) & 1)*65536);
            #pragma unroll 8
            for (int i = 0; i < 16; ++i) {
                int c = tid + i*256;
                us8v v = *(const us8v*)(s1 + (size_t)c*16);
                *(us8v*)(zbuf + (c & 63)*2048 + ((1024 + (c >> 6)*16) ^ ((c & 7) << 4))) = v;
            }
        }
        __syncthreads();
        #pragma unroll
        for (int kt = 16; kt < 32; ++kt) {
            us8v bfrag = *(const us8v*)(zbuf + rb + ((kt*64 + lhi*16) ^ swzr));
            acc0 = mfma16(Areg[kt*2+0], bfrag, acc0);
            acc1 = mfma16(Areg[kt*2+1], bfrag, acc1);
        }
        #pragma unroll
        for (int q = 0; q < 4; ++q) {
            gsum[lhi*4+q][wv*16+l15]    = acc0[q];
            gsum[16+lhi*4+q][wv*16+l15] = acc1[q];
        }
        __syncthreads();
        {
            int b = tid & 63, p0 = (tid >> 6) * 2;
            unsigned hw = 0;
            #pragma unroll
            for (int pp = 0; pp < 2; ++pp) {
                int p = p0 + pp;
                float gi = gsum[p][b]    + bias_l[p];
                float gf = gsum[8+p][b]  + bias_l[8+p];
                float gg = gsum[16+p][b] + bias_l[16+p];
                float go = gsum[24+p][b] + bias_l[24+p];
                float iv = sigmf(gi), fv = sigmf(gf);
                float gv = tanh_fast(gg), ov = sigmf(go);
                float cc = fv * (pp ? c1 : c0) + iv * gv;
                if (pp) c1 = cc; else c0 = cc;
                float h = ov * tanh_fast(cc);
                hw |= ((unsigned)f2bf(h)) << (16*pp);
            }
            __hip_atomic_store((unsigned*)(ring + (size_t)(t & 1)*65536 + (size_t)j*1024 + b*16 + (p0 << 1)),
                               hw, __ATOMIC_RELAXED, __HIP_MEMORY_SCOPE_AGENT);
        }
        __syncthreads();
        if (tid == 0)
            __hip_atomic_store(&flags[(size_t)(512 + t)*64 + j], 1u,
                               __ATOMIC_RELEASE, __HIP_MEMORY_SCOPE_AGENT);
    }
#undef WAIT_FLAGS
}

// ---------------- final projection: out = h1_final @ lin_w.T + lin_b ----------------
__global__ void final_linear(const char* __restrict__ ws,
                             const float* __restrict__ linw, const float* __restrict__ linb,
                             float* __restrict__ out)
{
    __shared__ float hrow[512];
    int b = blockIdx.x;        // 64
    int o = threadIdx.x;       // 64
    const char* ring = ws + OFF_RING;
    {
        // t=511 -> ring parity 1; layout [par][j][b][8]
        us8v v = *(const us8v*)(ring + 65536u + (size_t)o*1024 + (size_t)b*16);
        #pragma unroll
        for (int p = 0; p < 8; ++p)
            hrow[o*8+p] = __builtin_bit_cast(float, ((unsigned)v[p]) << 16);
    }
    __syncthreads();
    float acc = linb[o];
    const float* wrow = linw + o*512;
    #pragma unroll 8
    for (int k = 0; k < 512; ++k) acc += hrow[k] * wrow[k];
    out[b*64 + o] = acc;
}

extern "C" void kernel_launch(void* const* d_in, const int* in_sizes, int n_in,
                              void* d_out, int out_size, void* d_ws, size_t ws_size,
                              hipStream_t stream)
{
    const float* x    = (const float*)d_in[0];
    const float* wih0 = (const float*)d_in[1];
    const float* whh0 = (const float*)d_in[2];
    const float* bih0 = (const float*)d_in[3];
    const float* bhh0 = (const float*)d_in[4];
    const float* wih1 = (const float*)d_in[5];
    const float* whh1 = (const float*)d_in[6];
    const float* bih1 = (const float*)d_in[7];
    const float* bhh1 = (const float*)d_in[8];
    const float* linw = (const float*)d_in[9];
    const float* linb = (const float*)d_in[10];
    char* ws = (char*)d_ws;

    (void)hipMemsetAsync(ws + OFF_FLAGS, 0, 262144, stream);   // reset step flags each call
    hipLaunchKernelGGL(setup_kernel, dim3(1024), dim3(256), 0, stream,
                       x, wih0, whh0, bih0, bhh0, wih1, whh1, bih1, bhh1, ws);
    hipLaunchKernelGGL(lstm_persist, dim3(NJ), dim3(256), 0, stream, ws);
    hipLaunchKernelGGL(final_linear, dim3(64), dim3(64), 0, stream,
                       ws, linw, linb, (float*)d_out);
}

// Round 4
// 2573.488 us; speedup vs baseline: 4.7384x; 3.7349x over previous
//
#include <hip/hip_runtime.h>

#define TSEQ 512

typedef unsigned short us8v __attribute__((ext_vector_type(8)));
typedef __bf16 bf16x8 __attribute__((ext_vector_type(8)));
typedef float f32x4 __attribute__((ext_vector_type(4)));
typedef unsigned u32x4 __attribute__((ext_vector_type(4)));

// ---- workspace layout (bytes) ----
#define OFF_FLAGS 0u           // [1024 widx][4 bg][32 hg] u32 = 512 KiB (write-once)
#define OFF_BIAS  524288u      // 2*2048 f32
#define OFF_X16   540672u      // x bf16 [512 t][64 b][64 d] = 4 MiB
#define OFF_W0    4734976u     // Wcat0 bf16 [2048][576]
#define OFF_W1    7094272u     // Wcat1 bf16 [2048][1024]
#define OFF_Y0    11288576u    // y0 bf16 [512 t][4 bg][16 b][512 h] = 32 MiB (write-once)
#define OFF_RING  44843008u    // h1 ring bf16 [2 par][4 bg][16 b][512 h] = 128 KiB (reused!)

static __device__ __forceinline__ unsigned short f2bf(float f) {
    unsigned u = __builtin_bit_cast(unsigned, f);
    u += 0x7fffu + ((u >> 16) & 1u);            // RNE
    return (unsigned short)(u >> 16);
}
static __device__ __forceinline__ float sigmf(float x) { return 1.0f / (1.0f + __expf(-x)); }
static __device__ __forceinline__ float tanh_fast(float x) {
    float a = fabsf(x);
    float e = __expf(-2.0f * a);
    float t = (1.0f - e) / (1.0f + e);
    return copysignf(t, x);
}
static __device__ __forceinline__ f32x4 mfma16(us8v a, us8v b, f32x4 c) {
    return __builtin_amdgcn_mfma_f32_16x16x32_bf16(
        __builtin_bit_cast(bf16x8, a), __builtin_bit_cast(bf16x8, b), c, 0, 0, 0);
}

// ---------------- setup: fp32 -> bf16 conversions + concatenated weights ----------------
__global__ void setup_kernel(const float* __restrict__ x,
                             const float* __restrict__ wih0, const float* __restrict__ whh0,
                             const float* __restrict__ bih0, const float* __restrict__ bhh0,
                             const float* __restrict__ wih1, const float* __restrict__ whh1,
                             const float* __restrict__ bih1, const float* __restrict__ bhh1,
                             char* __restrict__ ws)
{
    unsigned idx = blockIdx.x * blockDim.x + threadIdx.x;
    unsigned stride = gridDim.x * blockDim.x;
    unsigned short* x16 = (unsigned short*)(ws + OFF_X16);
    unsigned short* w0  = (unsigned short*)(ws + OFF_W0);
    unsigned short* w1  = (unsigned short*)(ws + OFF_W1);
    float* bias = (float*)(ws + OFF_BIAS);
    const unsigned NX  = 64u*512u*64u;      // 2097152
    const unsigned NW0 = 2048u*576u;        // 1179648
    const unsigned NW1 = 2048u*1024u;       // 2097152
    const unsigned NT  = NX + NW0 + NW1 + 4096u;
    for (unsigned i = idx; i < NT; i += stride) {
        if (i < NX) {
            // transpose to [t][b][d]
            unsigned d = i & 63u, b = (i >> 6) & 63u, t = i >> 12;
            x16[i] = f2bf(x[((b << 9) + t) * 64u + d]);
        } else if (i < NX + NW0) {
            unsigned k = i - NX; unsigned r = k / 576u, c = k % 576u;
            float v = (c < 64u) ? wih0[r*64u + c] : whh0[r*512u + (c - 64u)];
            w0[k] = f2bf(v);
        } else if (i < NX + NW0 + NW1) {
            unsigned k = i - NX - NW0; unsigned r = k >> 10, c = k & 1023u;
            float v = (c < 512u) ? wih1[(r<<9) + c] : whh1[(r<<9) + (c - 512u)];
            w1[k] = f2bf(v);
        } else {
            unsigned k = i - NX - NW0 - NW1;   // 0..4095
            float v = (k < 2048u) ? (bih0[k] + bhh0[k]) : (bih1[k-2048u] + bhh1[k-2048u]);
            bias[k] = v;
        }
    }
}

// ---------------- persistent recurrence kernel ----------------
// 128 blocks = 4 batch-groups (bg, 16 batches each) x 32 h-groups (hg, 16 h each
// -> 64 gate rows). No placement assumptions: 4 independent 32-block recurrences.
// Sync through coherent memory-side L3: sc0sc1 write-through h/flag stores,
// sc0sc1 poll loads; write-once buffers read with plain cached loads.
__launch_bounds__(256, 1)
__global__ void lstm_persist(char* __restrict__ ws)
{
    const int tid  = threadIdx.x;
    const int kq   = tid >> 6;      // wave = K-quarter
    const int lane = tid & 63;
    const int l15  = lane & 15;     // A-row within tile / D-col (batch)
    const int lhi  = lane >> 4;     // k-sub within kt / D-row-group
    const int bg   = blockIdx.x & 3;
    const int hg   = blockIdx.x >> 2;

    unsigned* flags   = (unsigned*)(ws + OFF_FLAGS);
    const float* bias = (const float*)(ws + OFF_BIAS);
    const char*  x16  = ws + OFF_X16;
    char* y0   = ws + OFF_Y0;
    char* ring = ws + OFF_RING;

    __shared__ __align__(16) char zbuf[32768];   // [16 b][K] bf16, XOR-swizzled
    __shared__ float gsum[4*64*18];              // [kq][64 gate-rows][16 b pad 18]
    __shared__ float bias_l[64];

    // zero zbuf (h region must read as exact 0 at t=0)
    {
        u32x4 zz = {0u,0u,0u,0u};
        #pragma unroll
        for (int i = 0; i < 8; ++i) ((u32x4*)zbuf)[tid + i*256] = zz;
    }
    if (tid < 64) bias_l[tid] = bias[(tid >> 4)*512 + hg*16 + (tid & 15)];

    // per-thread cell state: thread owns (b = tid>>4, p = tid&15)
    float cst = 0.0f;

    // A fragments: A[m][kk], m = gate, kk = local k-tile of this wave
    us8v A[4][8];
    {
        const char* w0p = ws + OFF_W0;
        #pragma unroll
        for (int m = 0; m < 4; ++m) {
            const char* base = w0p + (size_t)(m*512 + hg*16 + l15)*1152 + lhi*16;
            #pragma unroll
            for (int kk = 0; kk < 4; ++kk)
                A[m][kk] = *(const us8v*)(base + (2 + kq*4 + kk)*64);   // h k-tiles
            if (kq < 2) A[m][4] = *(const us8v*)(base + kq*64);         // x k-tiles
        }
    }
    __syncthreads();

    const int swzb = (l15 & 7) << 4;
    const int rb0  = l15 * 1152;
    const int rb1  = l15 * 2048;

#define POLL(WIDX) do {                                                              \
        const unsigned* fp_ = flags + (size_t)(WIDX)*128 + bg*32 + (lane & 31);      \
        unsigned fv_;                                                                \
        do {                                                                         \
            asm volatile("global_load_dword %0, %1, off sc0 sc1\n\ts_waitcnt vmcnt(0)" \
                         : "=v"(fv_) : "v"(fp_) : "memory");                         \
        } while (!__all(fv_ != 0u));                                                 \
    } while (0)

    // ================= layer 0 : K = 576 = [x_t(64) | h0(512)] =================
    for (int t = 0; t < TSEQ; ++t) {
        if (tid < 128) {   // stage x[t] slice (2 KB, write-once data, cached)
            int c = tid * 16, b = c >> 7, o = c & 127;
            us8v v = *(const us8v*)(x16 + (size_t)t*8192 + bg*2048 + c);
            *(us8v*)(zbuf + b*1152 + (o ^ ((b & 7) << 4))) = v;
        }
        if (t > 0) {
            POLL(t-1);
            // stage h[t-1] = y0[t-1][bg]: 16 KB write-once -> plain cached loads
            const char* hs = y0 + ((size_t)(t-1)*4 + bg)*16384;
            #pragma unroll
            for (int i = 0; i < 4; ++i) {
                int c = tid + i*256;
                us8v v = *(const us8v*)(hs + (size_t)c*16);
                int b = c >> 6, o = (c & 63) * 16;
                *(us8v*)(zbuf + b*1152 + ((128 + o) ^ ((b & 7) << 4))) = v;
            }
        }
        __syncthreads();

        f32x4 acc[4] = {{0.f,0.f,0.f,0.f},{0.f,0.f,0.f,0.f},{0.f,0.f,0.f,0.f},{0.f,0.f,0.f,0.f}};
        #pragma unroll
        for (int kk = 0; kk < 4; ++kk) {
            us8v bf = *(const us8v*)(zbuf + rb0 + (((2 + kq*4 + kk)*64 + lhi*16) ^ swzb));
            #pragma unroll
            for (int m = 0; m < 4; ++m) acc[m] = mfma16(A[m][kk], bf, acc[m]);
        }
        if (kq < 2) {
            us8v bf = *(const us8v*)(zbuf + rb0 + ((kq*64 + lhi*16) ^ swzb));
            #pragma unroll
            for (int m = 0; m < 4; ++m) acc[m] = mfma16(A[m][4], bf, acc[m]);
        }
        #pragma unroll
        for (int m = 0; m < 4; ++m) {
            #pragma unroll
            for (int q = 0; q < 4; ++q)
                gsum[(kq*64 + m*16 + lhi*4 + q)*18 + l15] = acc[m][q];
        }
        __syncthreads();

        {   // activation: thread (b, p)
            int b = tid >> 4, p = tid & 15;
            float g4[4];
            #pragma unroll
            for (int g = 0; g < 4; ++g) {
                float s = bias_l[g*16 + p];
                #pragma unroll
                for (int kk = 0; kk < 4; ++kk) s += gsum[(kk*64 + g*16 + p)*18 + b];
                g4[g] = s;
            }
            float iv = sigmf(g4[0]), fv = sigmf(g4[1]);
            float gv = tanh_fast(g4[2]), ov = sigmf(g4[3]);
            cst = fv*cst + iv*gv;
            float h = ov * tanh_fast(cst);
            unsigned hv = f2bf(h);
            const char* dst = y0 + ((size_t)t*4 + bg)*16384 + b*1024 + (hg*16 + p)*2;
            asm volatile("global_store_short %0, %1, off sc0 sc1"
                         :: "v"(dst), "v"(hv) : "memory");
        }
        asm volatile("s_waitcnt vmcnt(0)" ::: "memory");   // release: h visible at L3
        __syncthreads();
        if (tid == 0) {
            unsigned one = 1;
            const unsigned* fq = flags + (size_t)t*128 + bg*32 + hg;
            asm volatile("global_store_dword %0, %1, off sc0 sc1"
                         :: "v"(fq), "v"(one) : "memory");
        }
    }

    // ---- reload A + bias for layer 1 (K = 1024 = [y0(512) | h1(512)]) ----
    {
        const char* w1p = ws + OFF_W1;
        #pragma unroll
        for (int m = 0; m < 4; ++m) {
            const char* base = w1p + (size_t)(m*512 + hg*16 + l15)*2048 + lhi*16;
            #pragma unroll
            for (int kk = 0; kk < 4; ++kk) {
                A[m][kk]     = *(const us8v*)(base + (kq*4 + kk)*64);        // y0 k-tiles
                A[m][kk + 4] = *(const us8v*)(base + (16 + kq*4 + kk)*64);   // h  k-tiles
            }
        }
    }
    if (tid < 64) bias_l[tid] = bias[2048 + (tid >> 4)*512 + hg*16 + (tid & 15)];
    __syncthreads();
    // cst carries over: layer1 initial c = layer0 final c (reference quirk)

    for (int t = 0; t < TSEQ; ++t) {
        {   // stage y0[t][bg] (write-once, flag-confirmed during layer 0) -- cached
            const char* s0 = y0 + ((size_t)t*4 + bg)*16384;
            #pragma unroll
            for (int i = 0; i < 4; ++i) {
                int c = tid + i*256;
                us8v v = *(const us8v*)(s0 + (size_t)c*16);
                int b = c >> 6, o = (c & 63) * 16;
                *(us8v*)(zbuf + b*2048 + (o ^ ((b & 7) << 4))) = v;
            }
        }
        __syncthreads();

        f32x4 acc[4] = {{0.f,0.f,0.f,0.f},{0.f,0.f,0.f,0.f},{0.f,0.f,0.f,0.f},{0.f,0.f,0.f,0.f}};
        #pragma unroll
        for (int kk = 0; kk < 4; ++kk) {   // y0-half MFMAs before the wait
            us8v bf = *(const us8v*)(zbuf + rb1 + (((kq*4 + kk)*64 + lhi*16) ^ swzb));
            #pragma unroll
            for (int m = 0; m < 4; ++m) acc[m] = mfma16(A[m][kk], bf, acc[m]);
        }
        {
            const int widx = (t == 0) ? 511 : (511 + t);
            POLL(widx);
            // h-half: ring is REUSED (parity) -> must bypass L1/L2 (sc0 sc1)
            const char* s1 = (t == 0) ? (y0 + ((size_t)511*4 + bg)*16384)
                                      : (ring + ((size_t)((t-1) & 1)*4 + bg)*16384);
            u32x4 d0, d1, d2, d3;
            const char* a0 = s1 + (size_t)tid*16;
            const char* a1 = s1 + (size_t)(tid + 256)*16;
            const char* a2 = s1 + (size_t)(tid + 512)*16;
            const char* a3 = s1 + (size_t)(tid + 768)*16;
            asm volatile("global_load_dwordx4 %0, %4, off sc0 sc1\n\t"
                         "global_load_dwordx4 %1, %5, off sc0 sc1\n\t"
                         "global_load_dwordx4 %2, %6, off sc0 sc1\n\t"
                         "global_load_dwordx4 %3, %7, off sc0 sc1\n\t"
                         "s_waitcnt vmcnt(0)"
                         : "=&v"(d0), "=&v"(d1), "=&v"(d2), "=&v"(d3)
                         : "v"(a0), "v"(a1), "v"(a2), "v"(a3) : "memory");
            int c0i = tid, c1i = tid + 256, c2i = tid + 512, c3i = tid + 768;
            *(u32x4*)(zbuf + (c0i >> 6)*2048 + ((1024 + (c0i & 63)*16) ^ (((c0i >> 6) & 7) << 4))) = d0;
            *(u32x4*)(zbuf + (c1i >> 6)*2048 + ((1024 + (c1i & 63)*16) ^ (((c1i >> 6) & 7) << 4))) = d1;
            *(u32x4*)(zbuf + (c2i >> 6)*2048 + ((1024 + (c2i & 63)*16) ^ (((c2i >> 6) & 7) << 4))) = d2;
            *(u32x4*)(zbuf + (c3i >> 6)*2048 + ((1024 + (c3i & 63)*16) ^ (((c3i >> 6) & 7) << 4))) = d3;
        }
        __syncthreads();

        #pragma unroll
        for (int kk = 0; kk < 4; ++kk) {   // h-half MFMAs
            us8v bf = *(const us8v*)(zbuf + rb1 + (((16 + kq*4 + kk)*64 + lhi*16) ^ swzb));
            #pragma unroll
            for (int m = 0; m < 4; ++m) acc[m] = mfma16(A[m][kk + 4], bf, acc[m]);
        }
        #pragma unroll
        for (int m = 0; m < 4; ++m) {
            #pragma unroll
            for (int q = 0; q < 4; ++q)
                gsum[(kq*64 + m*16 + lhi*4 + q)*18 + l15] = acc[m][q];
        }
        __syncthreads();

        {
            int b = tid >> 4, p = tid & 15;
            float g4[4];
            #pragma unroll
            for (int g = 0; g < 4; ++g) {
                float s = bias_l[g*16 + p];
                #pragma unroll
                for (int kk = 0; kk < 4; ++kk) s += gsum[(kk*64 + g*16 + p)*18 + b];
                g4[g] = s;
            }
            float iv = sigmf(g4[0]), fv = sigmf(g4[1]);
            float gv = tanh_fast(g4[2]), ov = sigmf(g4[3]);
            cst = fv*cst + iv*gv;
            float h = ov * tanh_fast(cst);
            unsigned hv = f2bf(h);
            const char* dst = ring + ((size_t)(t & 1)*4 + bg)*16384 + b*1024 + (hg*16 + p)*2;
            asm volatile("global_store_short %0, %1, off sc0 sc1"
                         :: "v"(dst), "v"(hv) : "memory");
        }
        asm volatile("s_waitcnt vmcnt(0)" ::: "memory");
        __syncthreads();
        if (tid == 0) {
            unsigned one = 1;
            const unsigned* fq = flags + (size_t)(512 + t)*128 + bg*32 + hg;
            asm volatile("global_store_dword %0, %1, off sc0 sc1"
                         :: "v"(fq), "v"(one) : "memory");
        }
    }
#undef POLL
}

// ---------------- final projection: out = h1_final @ lin_w.T + lin_b ----------------
__global__ void final_linear(const char* __restrict__ ws,
                             const float* __restrict__ linw, const float* __restrict__ linb,
                             float* __restrict__ out)
{
    __shared__ float hrow[512];
    int b = blockIdx.x;        // global batch 0..63
    int o = threadIdx.x;       // 64 outputs
    int bg = b >> 4, bl = b & 15;
    // t=511 -> ring parity 1
    const char* src = ws + OFF_RING + ((size_t)1*4 + bg)*16384 + (size_t)bl*1024;
    {
        us8v v = *(const us8v*)(src + o*16);
        #pragma unroll
        for (int p = 0; p < 8; ++p)
            hrow[o*8+p] = __builtin_bit_cast(float, ((unsigned)v[p]) << 16);
    }
    __syncthreads();
    float acc = linb[o];
    const float* wrow = linw + o*512;
    #pragma unroll 8
    for (int k = 0; k < 512; ++k) acc += hrow[k] * wrow[k];
    out[b*64 + o] = acc;
}

extern "C" void kernel_launch(void* const* d_in, const int* in_sizes, int n_in,
                              void* d_out, int out_size, void* d_ws, size_t ws_size,
                              hipStream_t stream)
{
    const float* x    = (const float*)d_in[0];
    const float* wih0 = (const float*)d_in[1];
    const float* whh0 = (const float*)d_in[2];
    const float* bih0 = (const float*)d_in[3];
    const float* bhh0 = (const float*)d_in[4];
    const float* wih1 = (const float*)d_in[5];
    const float* whh1 = (const float*)d_in[6];
    const float* bih1 = (const float*)d_in[7];
    const float* bhh1 = (const float*)d_in[8];
    const float* linw = (const float*)d_in[9];
    const float* linb = (const float*)d_in[10];
    char* ws = (char*)d_ws;

    // zero step flags (visible to lstm_persist via dispatch-boundary ordering)
    (void)hipMemsetAsync(ws + OFF_FLAGS, 0, 524288, stream);
    hipLaunchKernelGGL(setup_kernel, dim3(1024), dim3(256), 0, stream,
                       x, wih0, whh0, bih0, bhh0, wih1, whh1, bih1, bhh1, ws);
    hipLaunchKernelGGL(lstm_persist, dim3(128), dim3(256), 0, stream, ws);
    hipLaunchKernelGGL(final_linear, dim3(64), dim3(64), 0, stream,
                       ws, linw, linb, (float*)d_out);
}